// Round 2
// baseline (298.323 us; speedup 1.0000x reference)
//
#include <hip/hip_runtime.h>
#include <hip/hip_bf16.h>
#include <stdint.h>
#include <stddef.h>

typedef __bf16 bf16;
typedef bf16 bf16x8 __attribute__((ext_vector_type(8)));
typedef float f32x4 __attribute__((ext_vector_type(4)));

#define EPSN 1e-8f
#define TWO_PI 6.283185307179586f

#define NB 16384   // batch
#define NH 512     // hidden
#define NI 256     // input
#define KTOT 1280  // 512 + 512 + 256

__device__ __forceinline__ float2 cmul(float2 a, float2 b) {
  return make_float2(a.x * b.x - a.y * b.y, a.x * b.y + a.y * b.x);
}
// a * conj(b)
__device__ __forceinline__ float2 cmulconj(float2 a, float2 b) {
  return make_float2(a.x * b.x + a.y * b.y, a.y * b.x - a.x * b.y);
}
__device__ __forceinline__ float2 cadd(float2 a, float2 b) {
  return make_float2(a.x + b.x, a.y + b.y);
}
__device__ __forceinline__ int brev9(int i) {
  return (int)(__brev((unsigned)i) >> 23);
}

// ---------------------------------------------------------------------------
// Setup: d1,d2,d3 = exp(i*angles); v1,v2 = r/(||r||+eps). One block, 512 thr.
// ---------------------------------------------------------------------------
__global__ __launch_bounds__(512) void setup_kernel(
    const float* __restrict__ ang, const float* __restrict__ rre,
    const float* __restrict__ rim, float2* __restrict__ d1,
    float2* __restrict__ d2, float2* __restrict__ d3, float2* __restrict__ v1,
    float2* __restrict__ v2) {
  __shared__ float red[512];
  const int t = threadIdx.x;
  float s, c;
  __sincosf(ang[t], &s, &c);
  d1[t] = make_float2(c, s);
  __sincosf(ang[512 + t], &s, &c);
  d2[t] = make_float2(c, s);
  __sincosf(ang[1024 + t], &s, &c);
  d3[t] = make_float2(c, s);

  const float r1x = rre[t], r1y = rim[t];
  const float r2x = rre[512 + t], r2y = rim[512 + t];

  red[t] = r1x * r1x + r1y * r1y;
  __syncthreads();
  for (int off = 256; off > 0; off >>= 1) {
    if (t < off) red[t] += red[t + off];
    __syncthreads();
  }
  const float inv1 = 1.0f / (sqrtf(red[0]) + EPSN);
  __syncthreads();
  red[t] = r2x * r2x + r2y * r2y;
  __syncthreads();
  for (int off = 256; off > 0; off >>= 1) {
    if (t < off) red[t] += red[t + off];
    __syncthreads();
  }
  const float inv2 = 1.0f / (sqrtf(red[0]) + EPSN);
  v1[t] = make_float2(r1x * inv1, r1y * inv1);
  v2[t] = make_float2(r2x * inv2, r2y * inv2);
}

// ---------------------------------------------------------------------------
// Build U = D3 R2 F^-1 D2 Pi R1 F D1 by pushing basis vector e_j (block j)
// through the pipeline, and scatter column j into the packed bf16 B matrix:
//   Bm[2h  ][k] = [ U_re[h,:] | -U_im[h,:] | W_re[h,:] ]   (k = 0..1279)
//   Bm[2h+1][k] = [ U_im[h,:] |  U_re[h,:] | W_im[h,:] ]
// This kernel fills k<1024; pack_W fills k>=1024.
// ---------------------------------------------------------------------------
__global__ __launch_bounds__(256) void build_U(
    const float2* __restrict__ d1, const float2* __restrict__ d2,
    const float2* __restrict__ d3, const float2* __restrict__ v1,
    const float2* __restrict__ v2, const int* __restrict__ perm,
    bf16* __restrict__ Bm) {
  __shared__ float2 bufA[512];
  __shared__ float2 bufB[512];
  __shared__ float2 redw[4];
  __shared__ float2 bc;

  const int t = threadIdx.x;
  const int j = blockIdx.x;  // basis index / column of U
  const int j0 = t, j1 = t + 256;

  // input e_j: after D1, spike of value d1[j] at position j; bit-rev scatter
  {
    const float2 dj = d1[j];
    float2 z = make_float2(0.f, 0.f);
    bufA[brev9(j0)] = (j0 == j) ? dj : z;
    bufA[brev9(j1)] = (j1 == j) ? dj : z;
  }
  __syncthreads();

  // forward FFT
#pragma unroll
  for (int st = 0; st < 9; ++st) {
    const int half = 1 << st;
    const int pos = t & (half - 1);
    const int i0 = ((t >> st) << (st + 1)) + pos;
    const int i1 = i0 + half;
    const float angv = -TWO_PI * (float)pos / (float)(2 << st);
    float sn, cs;
    __sincosf(angv, &sn, &cs);
    float2 u = bufA[i0];
    float2 w = bufA[i1];
    float2 tw = make_float2(cs * w.x - sn * w.y, cs * w.y + sn * w.x);
    bufA[i0] = make_float2(u.x + tw.x, u.y + tw.y);
    bufA[i1] = make_float2(u.x - tw.x, u.y - tw.y);
    __syncthreads();
  }

  // dot1 = sum_i h_i * v1_i
  const float2 v1a = v1[j0], v1b = v1[j1];
  {
    float2 p = cadd(cmul(bufA[j0], v1a), cmul(bufA[j1], v1b));
    for (int off = 32; off > 0; off >>= 1) {
      p.x += __shfl_down(p.x, off);
      p.y += __shfl_down(p.y, off);
    }
    if ((t & 63) == 0) redw[t >> 6] = p;
    __syncthreads();
    if (t == 0) bc = cadd(cadd(redw[0], redw[1]), cadd(redw[2], redw[3]));
    __syncthreads();
  }
  const float2 dot1 = bc;

  // Householder 1
  {
    float2 c0 = cmulconj(dot1, v1a);
    float2 c1 = cmulconj(dot1, v1b);
    float2 a0 = bufA[j0], a1 = bufA[j1];
    bufA[j0] = make_float2(a0.x - 2.f * c0.x, a0.y - 2.f * c0.y);
    bufA[j1] = make_float2(a1.x - 2.f * c1.x, a1.y - 2.f * c1.y);
  }
  __syncthreads();

  // permute + x d2 + bit-rev scatter
  {
    int p0 = perm[j0], p1 = perm[j1];
    float2 g0 = cmul(d2[j0], bufA[p0]);
    float2 g1 = cmul(d2[j1], bufA[p1]);
    bufB[brev9(j0)] = g0;
    bufB[brev9(j1)] = g1;
  }
  __syncthreads();

  // inverse FFT (unscaled)
#pragma unroll
  for (int st = 0; st < 9; ++st) {
    const int half = 1 << st;
    const int pos = t & (half - 1);
    const int i0 = ((t >> st) << (st + 1)) + pos;
    const int i1 = i0 + half;
    const float angv = TWO_PI * (float)pos / (float)(2 << st);
    float sn, cs;
    __sincosf(angv, &sn, &cs);
    float2 u = bufB[i0];
    float2 w = bufB[i1];
    float2 tw = make_float2(cs * w.x - sn * w.y, cs * w.y + sn * w.x);
    bufB[i0] = make_float2(u.x + tw.x, u.y + tw.y);
    bufB[i1] = make_float2(u.x - tw.x, u.y - tw.y);
    __syncthreads();
  }

  // dot2 on unscaled ifft output
  const float2 v2a = v2[j0], v2b = v2[j1];
  {
    float2 q = cadd(cmul(bufB[j0], v2a), cmul(bufB[j1], v2b));
    for (int off = 32; off > 0; off >>= 1) {
      q.x += __shfl_down(q.x, off);
      q.y += __shfl_down(q.y, off);
    }
    if ((t & 63) == 0) redw[t >> 6] = q;
    __syncthreads();
    if (t == 0) bc = cadd(cadd(redw[0], redw[1]), cadd(redw[2], redw[3]));
    __syncthreads();
  }
  const float invN = 1.0f / 512.0f;
  const float2 dot2 = make_float2(bc.x * invN, bc.y * invN);

  // Householder2 + d3, then scatter U[:,j] into Bm (bf16)
#pragma unroll
  for (int e = 0; e < 2; ++e) {
    const int i = (e == 0) ? j0 : j1;
    const float2 vj = (e == 0) ? v2a : v2b;
    float2 h2 = make_float2(bufB[i].x * invN, bufB[i].y * invN);
    float2 c2 = cmulconj(dot2, vj);
    float2 hh = make_float2(h2.x - 2.f * c2.x, h2.y - 2.f * c2.y);
    float2 u = cmul(d3[i], hh);  // U[i][j]
    bf16* r0 = Bm + (size_t)(2 * i) * KTOT;
    bf16* r1 = Bm + (size_t)(2 * i + 1) * KTOT;
    r0[j] = (bf16)u.x;
    r0[512 + j] = (bf16)(-u.y);
    r1[j] = (bf16)u.y;
    r1[512 + j] = (bf16)u.x;
  }
}

// ---------------------------------------------------------------------------
// pack_W: Bm[2h][1024+k] = W_re[h][k]; Bm[2h+1][1024+k] = W_im[h][k].
// ---------------------------------------------------------------------------
__global__ __launch_bounds__(256) void pack_W(const float* __restrict__ wre,
                                              const float* __restrict__ wim,
                                              bf16* __restrict__ Bm) {
  const int h = blockIdx.x;
  const int k = threadIdx.x;
  Bm[(size_t)(2 * h) * KTOT + 1024 + k] = (bf16)wre[h * NI + k];
  Bm[(size_t)(2 * h + 1) * KTOT + 1024 + k] = (bf16)wim[h * NI + k];
}

// ---------------------------------------------------------------------------
// Fused GEMM + ModReLU:
//   out[b, n] = ModReLU-component( [hx_re|hx_im|x][b,:] . Bm[n,:] )
// M=16384, N=1024 physical (n=2h+parity), K=1280. 128x128 tile, 4 waves 2x2,
// 16x16x32 bf16 MFMA, 4x4 frags/wave. fp32->bf16 fused into A staging.
// Epilogue: shfl_xor(1) pairs re/im (col parity == lane parity), ModReLU,
// direct coalesced store to d_out (physical n axis == flat (h,2) axis).
// ---------------------------------------------------------------------------
__global__ __launch_bounds__(256) void gemm_fused(
    const float* __restrict__ hxre, const float* __restrict__ hxim,
    const float* __restrict__ x, const bf16* __restrict__ Bm,
    const float* __restrict__ beta, float* __restrict__ out) {
  __shared__ bf16 As[128 * 40];
  __shared__ bf16 Bs[128 * 40];

  const int t = threadIdx.x;
  const int lane = t & 63;
  const int wave = t >> 6;
  const int waveM = wave & 1;
  const int waveN = wave >> 1;
  const int nBase = blockIdx.x * 128;  // N fastest -> A panel L2/L3 reuse
  const int mBase = blockIdx.y * 128;

  f32x4 acc[4][4] = {};

  const int sr = t >> 2;       // A staging row 0..63 (+64)
  const int sc = (t & 3) * 8;  // A staging col: 0,8,16,24
  const int br = t >> 1;       // B staging row 0..127
  const int bco = (t & 1) * 16;
  const int lr = lane & 15;
  const int lq = lane >> 4;

  for (int kk = 0; kk < KTOT; kk += 32) {
    // segment select (wave-uniform scalar branch)
    const float* srcBase;
    int stride;
    if (kk < 512) {
      srcBase = hxre + kk;
      stride = 512;
    } else if (kk < 1024) {
      srcBase = hxim + (kk - 512);
      stride = 512;
    } else {
      srcBase = x + (kk - 1024);
      stride = 256;
    }
#pragma unroll
    for (int h = 0; h < 2; ++h) {
      const int row = sr + h * 64;
      const float* gp = srcBase + (size_t)(mBase + row) * stride + sc;
      float4 f0 = ((const float4*)gp)[0];
      float4 f1 = ((const float4*)gp)[1];
      bf16x8 va;
      va[0] = (bf16)f0.x; va[1] = (bf16)f0.y; va[2] = (bf16)f0.z; va[3] = (bf16)f0.w;
      va[4] = (bf16)f1.x; va[5] = (bf16)f1.y; va[6] = (bf16)f1.z; va[7] = (bf16)f1.w;
      *(bf16x8*)(&As[row * 40 + sc]) = va;
    }
    {
      const bf16* gq = Bm + (size_t)(nBase + br) * KTOT + kk + bco;
      bf16x8 b0 = ((const bf16x8*)gq)[0];
      bf16x8 b1 = ((const bf16x8*)gq)[1];
      *(bf16x8*)(&Bs[br * 40 + bco]) = b0;
      *(bf16x8*)(&Bs[br * 40 + bco + 8]) = b1;
    }
    __syncthreads();

    bf16x8 af[4], bfr[4];
#pragma unroll
    for (int mi = 0; mi < 4; ++mi)
      af[mi] = *(const bf16x8*)(&As[(waveM * 64 + mi * 16 + lr) * 40 + lq * 8]);
#pragma unroll
    for (int ni = 0; ni < 4; ++ni)
      bfr[ni] = *(const bf16x8*)(&Bs[(waveN * 64 + ni * 16 + lr) * 40 + lq * 8]);
#pragma unroll
    for (int mi = 0; mi < 4; ++mi)
#pragma unroll
      for (int ni = 0; ni < 4; ++ni)
        acc[mi][ni] = __builtin_amdgcn_mfma_f32_16x16x32_bf16(
            af[mi], bfr[ni], acc[mi][ni], 0, 0, 0);
    __syncthreads();
  }

  // Epilogue: C layout col=lane&15, row=(lane>>4)*4+reg. Physical col n:
  // even=re, odd=im of h=n>>1; col parity == lane parity.
  const int col = lane & 15;
  const int row0 = (lane >> 4) * 4;
  const int parity = lane & 1;
#pragma unroll
  for (int ni = 0; ni < 4; ++ni) {
    const int n = nBase + waveN * 64 + ni * 16 + col;
    const float bet = beta[n >> 1];
#pragma unroll
    for (int mi = 0; mi < 4; ++mi) {
      const int mrow = mBase + waveM * 64 + mi * 16 + row0;
#pragma unroll
      for (int r = 0; r < 4; ++r) {
        float a = acc[mi][ni][r];
        float o = __shfl_xor(a, 1);
        float re = parity ? o : a;
        float im = parity ? a : o;
        float mag = sqrtf(re * re + im * im);
        float s = mag + bet;
        float val;
        if (s <= 0.f)
          val = 0.f;
        else if (mag > 0.f)
          val = (parity ? im : re) * (s / mag);
        else
          val = parity ? 0.f : s;  // angle(0)==0 -> exp(i0)==1
        out[(size_t)(mrow + r) * 1024 + n] = val;
      }
    }
  }
}

// ---------------------------------------------------------------------------
extern "C" void kernel_launch(void* const* d_in, const int* in_sizes, int n_in,
                              void* d_out, int out_size, void* d_ws,
                              size_t ws_size, hipStream_t stream) {
  const float* x = (const float*)d_in[0];
  const float* hxre = (const float*)d_in[1];
  const float* hxim = (const float*)d_in[2];
  const float* ang = (const float*)d_in[3];
  const float* rre = (const float*)d_in[4];
  const float* rim = (const float*)d_in[5];
  const float* wre = (const float*)d_in[6];
  const float* wim = (const float*)d_in[7];
  const float* beta = (const float*)d_in[8];
  const int* perm = (const int*)d_in[9];

  char* ws = (char*)d_ws;
  float2* c_d1 = (float2*)ws;  // 5 x 512 float2 = 20 KiB
  float2* c_d2 = c_d1 + 512;
  float2* c_d3 = c_d2 + 512;
  float2* c_v1 = c_d3 + 512;
  float2* c_v2 = c_v1 + 512;
  bf16* Bm = (bf16*)(ws + 32768);  // 1024 x 1280 bf16 = 2.56 MiB

  setup_kernel<<<1, 512, 0, stream>>>(ang, rre, rim, c_d1, c_d2, c_d3, c_v1,
                                      c_v2);
  build_U<<<512, 256, 0, stream>>>(c_d1, c_d2, c_d3, c_v1, c_v2, perm, Bm);
  pack_W<<<512, 256, 0, stream>>>(wre, wim, Bm);
  gemm_fused<<<dim3(1024 / 128, NB / 128), 256, 0, stream>>>(
      hxre, hxim, x, Bm, beta, (float*)d_out);
}

// Round 3
// 249.946 us; speedup vs baseline: 1.1935x; 1.1935x over previous
//
#include <hip/hip_runtime.h>
#include <hip/hip_bf16.h>
#include <stdint.h>
#include <stddef.h>

typedef __bf16 bf16;
typedef bf16 bf16x8 __attribute__((ext_vector_type(8)));
typedef float f32x4 __attribute__((ext_vector_type(4)));

#define EPSN 1e-8f
#define TWO_PI 6.283185307179586f

#define NB 16384   // batch
#define NH 512     // hidden
#define NI 256     // input
#define KTOT 1280  // 512 + 512 + 256

__device__ __forceinline__ float2 cmul(float2 a, float2 b) {
  return make_float2(a.x * b.x - a.y * b.y, a.x * b.y + a.y * b.x);
}
// a * conj(b)
__device__ __forceinline__ float2 cmulconj(float2 a, float2 b) {
  return make_float2(a.x * b.x + a.y * b.y, a.y * b.x - a.x * b.y);
}
__device__ __forceinline__ float2 cadd(float2 a, float2 b) {
  return make_float2(a.x + b.x, a.y + b.y);
}
__device__ __forceinline__ int brev9(int i) {
  return (int)(__brev((unsigned)i) >> 23);
}

// async global->LDS, 16B per lane; lds dest = wave-uniform base + lane*16
__device__ __forceinline__ void gload16(const bf16* g, bf16* l) {
  __builtin_amdgcn_global_load_lds(
      (const __attribute__((address_space(1))) void*)g,
      (__attribute__((address_space(3))) void*)l, 16, 0, 0);
}

// ---------------------------------------------------------------------------
// Setup: d1,d2,d3 = exp(i*angles); v1,v2 = r/(||r||+eps). One block, 512 thr.
// ---------------------------------------------------------------------------
__global__ __launch_bounds__(512) void setup_kernel(
    const float* __restrict__ ang, const float* __restrict__ rre,
    const float* __restrict__ rim, float2* __restrict__ d1,
    float2* __restrict__ d2, float2* __restrict__ d3, float2* __restrict__ v1,
    float2* __restrict__ v2) {
  __shared__ float red[512];
  const int t = threadIdx.x;
  float s, c;
  __sincosf(ang[t], &s, &c);
  d1[t] = make_float2(c, s);
  __sincosf(ang[512 + t], &s, &c);
  d2[t] = make_float2(c, s);
  __sincosf(ang[1024 + t], &s, &c);
  d3[t] = make_float2(c, s);

  const float r1x = rre[t], r1y = rim[t];
  const float r2x = rre[512 + t], r2y = rim[512 + t];

  red[t] = r1x * r1x + r1y * r1y;
  __syncthreads();
  for (int off = 256; off > 0; off >>= 1) {
    if (t < off) red[t] += red[t + off];
    __syncthreads();
  }
  const float inv1 = 1.0f / (sqrtf(red[0]) + EPSN);
  __syncthreads();
  red[t] = r2x * r2x + r2y * r2y;
  __syncthreads();
  for (int off = 256; off > 0; off >>= 1) {
    if (t < off) red[t] += red[t + off];
    __syncthreads();
  }
  const float inv2 = 1.0f / (sqrtf(red[0]) + EPSN);
  v1[t] = make_float2(r1x * inv1, r1y * inv1);
  v2[t] = make_float2(r2x * inv2, r2y * inv2);
}

// ---------------------------------------------------------------------------
// Build U = D3 R2 F^-1 D2 Pi R1 F D1 columnwise (block j = basis e_j) and
// scatter into packed bf16 B matrix:
//   Bm[2h  ][k] = [ U_re[h,:] | -U_im[h,:] | W_re[h,:] ]
//   Bm[2h+1][k] = [ U_im[h,:] |  U_re[h,:] | W_im[h,:] ]
// ---------------------------------------------------------------------------
__global__ __launch_bounds__(256) void build_U(
    const float2* __restrict__ d1, const float2* __restrict__ d2,
    const float2* __restrict__ d3, const float2* __restrict__ v1,
    const float2* __restrict__ v2, const int* __restrict__ perm,
    bf16* __restrict__ Bm) {
  __shared__ float2 bufA[512];
  __shared__ float2 bufB[512];
  __shared__ float2 redw[4];
  __shared__ float2 bc;

  const int t = threadIdx.x;
  const int j = blockIdx.x;
  const int j0 = t, j1 = t + 256;

  {
    const float2 dj = d1[j];
    float2 z = make_float2(0.f, 0.f);
    bufA[brev9(j0)] = (j0 == j) ? dj : z;
    bufA[brev9(j1)] = (j1 == j) ? dj : z;
  }
  __syncthreads();

#pragma unroll
  for (int st = 0; st < 9; ++st) {
    const int half = 1 << st;
    const int pos = t & (half - 1);
    const int i0 = ((t >> st) << (st + 1)) + pos;
    const int i1 = i0 + half;
    const float angv = -TWO_PI * (float)pos / (float)(2 << st);
    float sn, cs;
    __sincosf(angv, &sn, &cs);
    float2 u = bufA[i0];
    float2 w = bufA[i1];
    float2 tw = make_float2(cs * w.x - sn * w.y, cs * w.y + sn * w.x);
    bufA[i0] = make_float2(u.x + tw.x, u.y + tw.y);
    bufA[i1] = make_float2(u.x - tw.x, u.y - tw.y);
    __syncthreads();
  }

  const float2 v1a = v1[j0], v1b = v1[j1];
  {
    float2 p = cadd(cmul(bufA[j0], v1a), cmul(bufA[j1], v1b));
    for (int off = 32; off > 0; off >>= 1) {
      p.x += __shfl_down(p.x, off);
      p.y += __shfl_down(p.y, off);
    }
    if ((t & 63) == 0) redw[t >> 6] = p;
    __syncthreads();
    if (t == 0) bc = cadd(cadd(redw[0], redw[1]), cadd(redw[2], redw[3]));
    __syncthreads();
  }
  const float2 dot1 = bc;

  {
    float2 c0 = cmulconj(dot1, v1a);
    float2 c1 = cmulconj(dot1, v1b);
    float2 a0 = bufA[j0], a1 = bufA[j1];
    bufA[j0] = make_float2(a0.x - 2.f * c0.x, a0.y - 2.f * c0.y);
    bufA[j1] = make_float2(a1.x - 2.f * c1.x, a1.y - 2.f * c1.y);
  }
  __syncthreads();

  {
    int p0 = perm[j0], p1 = perm[j1];
    float2 g0 = cmul(d2[j0], bufA[p0]);
    float2 g1 = cmul(d2[j1], bufA[p1]);
    bufB[brev9(j0)] = g0;
    bufB[brev9(j1)] = g1;
  }
  __syncthreads();

#pragma unroll
  for (int st = 0; st < 9; ++st) {
    const int half = 1 << st;
    const int pos = t & (half - 1);
    const int i0 = ((t >> st) << (st + 1)) + pos;
    const int i1 = i0 + half;
    const float angv = TWO_PI * (float)pos / (float)(2 << st);
    float sn, cs;
    __sincosf(angv, &sn, &cs);
    float2 u = bufB[i0];
    float2 w = bufB[i1];
    float2 tw = make_float2(cs * w.x - sn * w.y, cs * w.y + sn * w.x);
    bufB[i0] = make_float2(u.x + tw.x, u.y + tw.y);
    bufB[i1] = make_float2(u.x - tw.x, u.y - tw.y);
    __syncthreads();
  }

  const float2 v2a = v2[j0], v2b = v2[j1];
  {
    float2 q = cadd(cmul(bufB[j0], v2a), cmul(bufB[j1], v2b));
    for (int off = 32; off > 0; off >>= 1) {
      q.x += __shfl_down(q.x, off);
      q.y += __shfl_down(q.y, off);
    }
    if ((t & 63) == 0) redw[t >> 6] = q;
    __syncthreads();
    if (t == 0) bc = cadd(cadd(redw[0], redw[1]), cadd(redw[2], redw[3]));
    __syncthreads();
  }
  const float invN = 1.0f / 512.0f;
  const float2 dot2 = make_float2(bc.x * invN, bc.y * invN);

#pragma unroll
  for (int e = 0; e < 2; ++e) {
    const int i = (e == 0) ? j0 : j1;
    const float2 vj = (e == 0) ? v2a : v2b;
    float2 h2 = make_float2(bufB[i].x * invN, bufB[i].y * invN);
    float2 c2 = cmulconj(dot2, vj);
    float2 hh = make_float2(h2.x - 2.f * c2.x, h2.y - 2.f * c2.y);
    float2 u = cmul(d3[i], hh);  // U[i][j]
    bf16* r0 = Bm + (size_t)(2 * i) * KTOT;
    bf16* r1 = Bm + (size_t)(2 * i + 1) * KTOT;
    r0[j] = (bf16)u.x;
    r0[512 + j] = (bf16)(-u.y);
    r1[j] = (bf16)u.y;
    r1[512 + j] = (bf16)u.x;
  }
}

// ---------------------------------------------------------------------------
// pack_W: Bm[2h][1024+k] = W_re[h][k]; Bm[2h+1][1024+k] = W_im[h][k].
// ---------------------------------------------------------------------------
__global__ __launch_bounds__(256) void pack_W(const float* __restrict__ wre,
                                              const float* __restrict__ wim,
                                              bf16* __restrict__ Bm) {
  const int h = blockIdx.x;
  const int k = threadIdx.x;
  Bm[(size_t)(2 * h) * KTOT + 1024 + k] = (bf16)wre[h * NI + k];
  Bm[(size_t)(2 * h + 1) * KTOT + 1024 + k] = (bf16)wim[h * NI + k];
}

// ---------------------------------------------------------------------------
// pack_A: Apack[b][0:512|512:1024|1024:1280] = bf16([hxre|hxim|x][b]).
// One thread = one 8-elem octet (32B read, 16B write), fully coalesced.
// ---------------------------------------------------------------------------
__global__ __launch_bounds__(256) void pack_A(const float* __restrict__ hxre,
                                              const float* __restrict__ hxim,
                                              const float* __restrict__ x,
                                              bf16* __restrict__ Apack) {
  const int tid = blockIdx.x * 256 + threadIdx.x;  // 0 .. 16384*160-1
  const int b = tid / 160;
  const int o = tid - b * 160;
  const float* src;
  if (o < 64)
    src = hxre + (size_t)b * 512 + o * 8;
  else if (o < 128)
    src = hxim + (size_t)b * 512 + (o - 64) * 8;
  else
    src = x + (size_t)b * 256 + (o - 128) * 8;
  float4 f0 = ((const float4*)src)[0];
  float4 f1 = ((const float4*)src)[1];
  bf16x8 v;
  v[0] = (bf16)f0.x; v[1] = (bf16)f0.y; v[2] = (bf16)f0.z; v[3] = (bf16)f0.w;
  v[4] = (bf16)f1.x; v[5] = (bf16)f1.y; v[6] = (bf16)f1.z; v[7] = (bf16)f1.w;
  *(bf16x8*)(Apack + (size_t)b * KTOT + o * 8) = v;
}

// ---------------------------------------------------------------------------
// Fused GEMM + ModReLU: out[b,n] = ModReLU-comp( Apack[b,:] . Bm[n,:] ).
// M=16384, N=1024, K=1280. 128x128 tile, BK=64, 4 waves 2x2, 16x16x32 bf16
// MFMA 4x4 frags/wave. global_load_lds(16B) staging, unpadded [128][64] LDS
// tiles (ds_read_b128 fragment pattern is bank-group balanced). XCD swizzle:
// id&7 -> XCD, each XCD owns 16 M-panels so A panels are single-L2-resident.
// ---------------------------------------------------------------------------
__global__ __launch_bounds__(256) void gemm_fused(
    const bf16* __restrict__ Apack, const bf16* __restrict__ Bm,
    const float* __restrict__ beta, float* __restrict__ out) {
  __shared__ bf16 As[128 * 64];
  __shared__ bf16 Bs[128 * 64];

  const int t = threadIdx.x;
  const int lane = t & 63;
  const int wv = t >> 6;

  const int id = blockIdx.x;           // 0..1023
  const int xcd = id & 7;
  const int lix = id >> 3;             // 0..127
  const int mBase = (xcd * 16 + (lix >> 3)) * 128;
  const int nBase = (lix & 7) * 128;

  // staging: wave wv covers rows [wv*32, wv*32+32), 4 loads x 8 rows each;
  // lane -> row = +lane/8, octet = lane%8; LDS dest = base + lane*16B.
  const int srow = wv * 32 + (lane >> 3);
  const int soct = lane & 7;
  const bf16* gA = Apack + (size_t)(mBase + srow) * KTOT + soct * 8;
  const bf16* gB = Bm + (size_t)(nBase + srow) * KTOT + soct * 8;
  bf16* lA = As + (wv * 32) * 64;
  bf16* lB = Bs + (wv * 32) * 64;

  const int lr = lane & 15;
  const int lq = lane >> 4;
  const int waveM = wv & 1;
  const int waveN = wv >> 1;

  f32x4 acc[4][4] = {};

  for (int kk = 0; kk < KTOT; kk += 64) {
#pragma unroll
    for (int i = 0; i < 4; ++i) {
      gload16(gA + kk + (size_t)(i * 8) * KTOT, lA + i * 8 * 64);
      gload16(gB + kk + (size_t)(i * 8) * KTOT, lB + i * 8 * 64);
    }
    __syncthreads();  // drains vmcnt (global_load_lds) for all waves

#pragma unroll
    for (int kh = 0; kh < 2; ++kh) {
      bf16x8 af[4], bfr[4];
#pragma unroll
      for (int mi = 0; mi < 4; ++mi)
        af[mi] = *(const bf16x8*)(&As[(waveM * 64 + mi * 16 + lr) * 64 +
                                      kh * 32 + lq * 8]);
#pragma unroll
      for (int ni = 0; ni < 4; ++ni)
        bfr[ni] = *(const bf16x8*)(&Bs[(waveN * 64 + ni * 16 + lr) * 64 +
                                       kh * 32 + lq * 8]);
#pragma unroll
      for (int mi = 0; mi < 4; ++mi)
#pragma unroll
        for (int ni = 0; ni < 4; ++ni)
          acc[mi][ni] = __builtin_amdgcn_mfma_f32_16x16x32_bf16(
              af[mi], bfr[ni], acc[mi][ni], 0, 0, 0);
    }
    __syncthreads();
  }

  // Epilogue: C layout col=lane&15, row=(lane>>4)*4+reg. Physical col n:
  // even=re, odd=im of h=n>>1; col parity == lane parity -> shfl_xor(1).
  const int col = lane & 15;
  const int row0 = (lane >> 4) * 4;
  const int parity = lane & 1;
#pragma unroll
  for (int ni = 0; ni < 4; ++ni) {
    const int n = nBase + waveN * 64 + ni * 16 + col;
    const float bet = beta[n >> 1];
#pragma unroll
    for (int mi = 0; mi < 4; ++mi) {
      const int mrow = mBase + waveM * 64 + mi * 16 + row0;
#pragma unroll
      for (int r = 0; r < 4; ++r) {
        float a = acc[mi][ni][r];
        float o = __shfl_xor(a, 1);
        float re = parity ? o : a;
        float im = parity ? a : o;
        float mag = sqrtf(re * re + im * im);
        float s = mag + bet;
        float val;
        if (s <= 0.f)
          val = 0.f;
        else if (mag > 0.f)
          val = (parity ? im : re) * (s / mag);
        else
          val = parity ? 0.f : s;  // angle(0)==0 -> exp(i0)==1
        out[(size_t)(mrow + r) * 1024 + n] = val;
      }
    }
  }
}

// ---------------------------------------------------------------------------
extern "C" void kernel_launch(void* const* d_in, const int* in_sizes, int n_in,
                              void* d_out, int out_size, void* d_ws,
                              size_t ws_size, hipStream_t stream) {
  const float* x = (const float*)d_in[0];
  const float* hxre = (const float*)d_in[1];
  const float* hxim = (const float*)d_in[2];
  const float* ang = (const float*)d_in[3];
  const float* rre = (const float*)d_in[4];
  const float* rim = (const float*)d_in[5];
  const float* wre = (const float*)d_in[6];
  const float* wim = (const float*)d_in[7];
  const float* beta = (const float*)d_in[8];
  const int* perm = (const int*)d_in[9];

  char* ws = (char*)d_ws;
  float2* c_d1 = (float2*)ws;  // 5 x 512 float2 = 20 KiB (pad to 32 KiB)
  float2* c_d2 = c_d1 + 512;
  float2* c_d3 = c_d2 + 512;
  float2* c_v1 = c_d3 + 512;
  float2* c_v2 = c_v1 + 512;
  bf16* Bm = (bf16*)(ws + 32768);                     // 1024x1280 bf16, 2.5 MiB
  bf16* Apack = (bf16*)(ws + 32768 + (size_t)1024 * KTOT * 2);  // 16384x1280 bf16, 40 MiB

  setup_kernel<<<1, 512, 0, stream>>>(ang, rre, rim, c_d1, c_d2, c_d3, c_v1,
                                      c_v2);
  build_U<<<512, 256, 0, stream>>>(c_d1, c_d2, c_d3, c_v1, c_v2, perm, Bm);
  pack_W<<<512, 256, 0, stream>>>(wre, wim, Bm);
  pack_A<<<(NB * 160) / 256, 256, 0, stream>>>(hxre, hxim, x, Apack);
  gemm_fused<<<1024, 256, 0, stream>>>(Apack, Bm, beta, (float*)d_out);
}

// Round 4
// 223.090 us; speedup vs baseline: 1.3372x; 1.1204x over previous
//
#include <hip/hip_runtime.h>
#include <hip/hip_bf16.h>
#include <stdint.h>
#include <stddef.h>

typedef __bf16 bf16;
typedef bf16 bf16x8 __attribute__((ext_vector_type(8)));
typedef float f32x4 __attribute__((ext_vector_type(4)));

#define EPSN 1e-8f
#define TWO_PI 6.283185307179586f

#define NB 16384   // batch
#define NH 512     // hidden
#define NI 256     // input
#define KTOT 1280  // 512 + 512 + 256

__device__ __forceinline__ float2 cmul(float2 a, float2 b) {
  return make_float2(a.x * b.x - a.y * b.y, a.x * b.y + a.y * b.x);
}
// a * conj(b)
__device__ __forceinline__ float2 cmulconj(float2 a, float2 b) {
  return make_float2(a.x * b.x + a.y * b.y, a.y * b.x - a.x * b.y);
}
__device__ __forceinline__ float2 cadd(float2 a, float2 b) {
  return make_float2(a.x + b.x, a.y + b.y);
}
__device__ __forceinline__ int brev9(int i) {
  return (int)(__brev((unsigned)i) >> 23);
}

// async global->LDS, 16B per lane; lds dest = wave-uniform base + lane*16
__device__ __forceinline__ void gload16(const bf16* g, bf16* l) {
  __builtin_amdgcn_global_load_lds(
      (const __attribute__((address_space(1))) void*)g,
      (__attribute__((address_space(3))) void*)l, 16, 0, 0);
}

// ---------------------------------------------------------------------------
// build_U (fused with setup + pack_W). Block j pushes basis vector e_j
// through U = D3 R2 F^-1 D2 Pi R1 F D1 and scatters column j into the packed
// bf16 B matrix:
//   Bm[2h  ][k] = [ U_re[h,:] | -U_im[h,:] | W_re[h,:] ]
//   Bm[2h+1][k] = [ U_im[h,:] |  U_re[h,:] | W_im[h,:] ]
// Norms for v1,v2 are recomputed per block (redundant but trivial); d1,d2,d3
// via sincos on the fly. Block j also packs W rows h=j (k>=1024).
// ---------------------------------------------------------------------------
__global__ __launch_bounds__(256) void build_U(
    const float* __restrict__ ang, const float* __restrict__ rre,
    const float* __restrict__ rim, const float* __restrict__ wre,
    const float* __restrict__ wim, const int* __restrict__ perm,
    bf16* __restrict__ Bm) {
  __shared__ float2 bufA[512];
  __shared__ float2 bufB[512];
  __shared__ float2 redw[4];
  __shared__ float2 bc;
  __shared__ float2 red2[256];

  const int t = threadIdx.x;
  const int j = blockIdx.x;
  const int j0 = t, j1 = t + 256;

  // --- setup (per-block redundant): norms of r1, r2 ---
  const float r1x0 = rre[j0], r1y0 = rim[j0];
  const float r1x1 = rre[j1], r1y1 = rim[j1];
  const float r2x0 = rre[512 + j0], r2y0 = rim[512 + j0];
  const float r2x1 = rre[512 + j1], r2y1 = rim[512 + j1];
  red2[t] = make_float2(r1x0 * r1x0 + r1y0 * r1y0 + r1x1 * r1x1 + r1y1 * r1y1,
                        r2x0 * r2x0 + r2y0 * r2y0 + r2x1 * r2x1 + r2y1 * r2y1);
  __syncthreads();
  for (int off = 128; off > 0; off >>= 1) {
    if (t < off) {
      red2[t].x += red2[t + off].x;
      red2[t].y += red2[t + off].y;
    }
    __syncthreads();
  }
  const float inv1 = 1.0f / (sqrtf(red2[0].x) + EPSN);
  const float inv2 = 1.0f / (sqrtf(red2[0].y) + EPSN);
  const float2 v1a = make_float2(r1x0 * inv1, r1y0 * inv1);
  const float2 v1b = make_float2(r1x1 * inv1, r1y1 * inv1);
  const float2 v2a = make_float2(r2x0 * inv2, r2y0 * inv2);
  const float2 v2b = make_float2(r2x1 * inv2, r2y1 * inv2);

  // --- init: after D1, spike d1[j] at position j; bit-rev scatter ---
  {
    float sj, cj;
    __sincosf(ang[j], &sj, &cj);
    const float2 dj = make_float2(cj, sj);
    float2 z = make_float2(0.f, 0.f);
    bufA[brev9(j0)] = (j0 == j) ? dj : z;
    bufA[brev9(j1)] = (j1 == j) ? dj : z;
  }
  __syncthreads();

  // forward FFT
#pragma unroll
  for (int st = 0; st < 9; ++st) {
    const int half = 1 << st;
    const int pos = t & (half - 1);
    const int i0 = ((t >> st) << (st + 1)) + pos;
    const int i1 = i0 + half;
    const float angv = -TWO_PI * (float)pos / (float)(2 << st);
    float sn, cs;
    __sincosf(angv, &sn, &cs);
    float2 u = bufA[i0];
    float2 w = bufA[i1];
    float2 tw = make_float2(cs * w.x - sn * w.y, cs * w.y + sn * w.x);
    bufA[i0] = make_float2(u.x + tw.x, u.y + tw.y);
    bufA[i1] = make_float2(u.x - tw.x, u.y - tw.y);
    __syncthreads();
  }

  // dot1 = sum_i h_i * v1_i
  {
    float2 p = cadd(cmul(bufA[j0], v1a), cmul(bufA[j1], v1b));
    for (int off = 32; off > 0; off >>= 1) {
      p.x += __shfl_down(p.x, off);
      p.y += __shfl_down(p.y, off);
    }
    if ((t & 63) == 0) redw[t >> 6] = p;
    __syncthreads();
    if (t == 0) bc = cadd(cadd(redw[0], redw[1]), cadd(redw[2], redw[3]));
    __syncthreads();
  }
  const float2 dot1 = bc;

  // Householder 1
  {
    float2 c0 = cmulconj(dot1, v1a);
    float2 c1 = cmulconj(dot1, v1b);
    float2 a0 = bufA[j0], a1 = bufA[j1];
    bufA[j0] = make_float2(a0.x - 2.f * c0.x, a0.y - 2.f * c0.y);
    bufA[j1] = make_float2(a1.x - 2.f * c1.x, a1.y - 2.f * c1.y);
  }
  __syncthreads();

  // permute + x d2 + bit-rev scatter
  {
    int p0 = perm[j0], p1 = perm[j1];
    float s0, c0, s1, c1;
    __sincosf(ang[512 + j0], &s0, &c0);
    __sincosf(ang[512 + j1], &s1, &c1);
    float2 g0 = cmul(make_float2(c0, s0), bufA[p0]);
    float2 g1 = cmul(make_float2(c1, s1), bufA[p1]);
    bufB[brev9(j0)] = g0;
    bufB[brev9(j1)] = g1;
  }
  __syncthreads();

  // inverse FFT (unscaled)
#pragma unroll
  for (int st = 0; st < 9; ++st) {
    const int half = 1 << st;
    const int pos = t & (half - 1);
    const int i0 = ((t >> st) << (st + 1)) + pos;
    const int i1 = i0 + half;
    const float angv = TWO_PI * (float)pos / (float)(2 << st);
    float sn, cs;
    __sincosf(angv, &sn, &cs);
    float2 u = bufB[i0];
    float2 w = bufB[i1];
    float2 tw = make_float2(cs * w.x - sn * w.y, cs * w.y + sn * w.x);
    bufB[i0] = make_float2(u.x + tw.x, u.y + tw.y);
    bufB[i1] = make_float2(u.x - tw.x, u.y - tw.y);
    __syncthreads();
  }

  // dot2 on unscaled ifft output
  {
    float2 q = cadd(cmul(bufB[j0], v2a), cmul(bufB[j1], v2b));
    for (int off = 32; off > 0; off >>= 1) {
      q.x += __shfl_down(q.x, off);
      q.y += __shfl_down(q.y, off);
    }
    if ((t & 63) == 0) redw[t >> 6] = q;
    __syncthreads();
    if (t == 0) bc = cadd(cadd(redw[0], redw[1]), cadd(redw[2], redw[3]));
    __syncthreads();
  }
  const float invN = 1.0f / 512.0f;
  const float2 dot2 = make_float2(bc.x * invN, bc.y * invN);

  // Householder2 + d3, scatter U[:,j] into Bm
#pragma unroll
  for (int e = 0; e < 2; ++e) {
    const int i = (e == 0) ? j0 : j1;
    const float2 vj = (e == 0) ? v2a : v2b;
    float2 h2 = make_float2(bufB[i].x * invN, bufB[i].y * invN);
    float2 c2 = cmulconj(dot2, vj);
    float2 hh = make_float2(h2.x - 2.f * c2.x, h2.y - 2.f * c2.y);
    float s3, c3;
    __sincosf(ang[1024 + i], &s3, &c3);
    float2 u = cmul(make_float2(c3, s3), hh);  // U[i][j]
    bf16* r0 = Bm + (size_t)(2 * i) * KTOT;
    bf16* r1 = Bm + (size_t)(2 * i + 1) * KTOT;
    r0[j] = (bf16)u.x;
    r0[512 + j] = (bf16)(-u.y);
    r1[j] = (bf16)u.y;
    r1[512 + j] = (bf16)u.x;
  }

  // --- pack_W for h = j (independent of pipeline state) ---
  Bm[(size_t)(2 * j) * KTOT + 1024 + t] = (bf16)wre[j * NI + t];
  Bm[(size_t)(2 * j + 1) * KTOT + 1024 + t] = (bf16)wim[j * NI + t];
}

// ---------------------------------------------------------------------------
// pack_A: Apack[b][0:512|512:1024|1024:1280] = bf16([hxre|hxim|x][b]).
// One thread = one 8-elem octet (32B read, 16B write), fully coalesced.
// ---------------------------------------------------------------------------
__global__ __launch_bounds__(256) void pack_A(const float* __restrict__ hxre,
                                              const float* __restrict__ hxim,
                                              const float* __restrict__ x,
                                              bf16* __restrict__ Apack) {
  const int tid = blockIdx.x * 256 + threadIdx.x;  // 0 .. 16384*160-1
  const int b = tid / 160;
  const int o = tid - b * 160;
  const float* src;
  if (o < 64)
    src = hxre + (size_t)b * 512 + o * 8;
  else if (o < 128)
    src = hxim + (size_t)b * 512 + (o - 64) * 8;
  else
    src = x + (size_t)b * 256 + (o - 128) * 8;
  float4 f0 = ((const float4*)src)[0];
  float4 f1 = ((const float4*)src)[1];
  bf16x8 v;
  v[0] = (bf16)f0.x; v[1] = (bf16)f0.y; v[2] = (bf16)f0.z; v[3] = (bf16)f0.w;
  v[4] = (bf16)f1.x; v[5] = (bf16)f1.y; v[6] = (bf16)f1.z; v[7] = (bf16)f1.w;
  *(bf16x8*)(Apack + (size_t)b * KTOT + o * 8) = v;
}

// ---------------------------------------------------------------------------
// Fused GEMM + ModReLU: out[b,n] = ModReLU-comp( Apack[b,:] . Bm[n,:] ).
// M=16384, N=1024, K=1280. 128x128 tile, BK=64, 4 waves 2x2, 16x16x32 bf16
// MFMA 4x4 frags/wave. global_load_lds(16B) staging.
//
// LDS bank-conflict fix (XOR chunk swizzle): LDS row = 8 chunks of 16B;
// physical chunk p of row r holds logical chunk p ^ (r&7). Staging achieves
// this by permuting the GLOBAL source chunk per lane (logical chunk =
// (lane&7)^(lane>>3)) since the LDS dest of global_load_lds is fixed at
// base + lane*16B. Fragment ds_read_b128 then uses chunk (kh*4+lq)^(lr&7):
// each consecutive 8-lane group covers all 8 chunks -> all 32 banks,
// conflict-free. Global reads stay coalesced (permutation within 128B).
//
// XCD swizzle: id&7 -> XCD, each XCD owns 16 M-panels (A single-L2-resident).
// ---------------------------------------------------------------------------
__global__ __launch_bounds__(256) void gemm_fused(
    const bf16* __restrict__ Apack, const bf16* __restrict__ Bm,
    const float* __restrict__ beta, float* __restrict__ out) {
  __shared__ bf16 As[128 * 64];
  __shared__ bf16 Bs[128 * 64];

  const int t = threadIdx.x;
  const int lane = t & 63;
  const int wv = t >> 6;

  const int id = blockIdx.x;  // 0..1023
  const int xcd = id & 7;
  const int lix = id >> 3;    // 0..127
  const int mBase = (xcd * 16 + (lix >> 3)) * 128;
  const int nBase = (lix & 7) * 128;

  // staging: wave wv covers rows [wv*32, wv*32+32), 4 loads x 8 rows each;
  // row = +lane/8; global chunk = (lane&7) ^ (lane>>3)  [see swizzle note]
  const int srow = wv * 32 + (lane >> 3);
  const int soct = (lane & 7) ^ (lane >> 3);
  const bf16* gA = Apack + (size_t)(mBase + srow) * KTOT + soct * 8;
  const bf16* gB = Bm + (size_t)(nBase + srow) * KTOT + soct * 8;
  bf16* lA = As + (wv * 32) * 64;
  bf16* lB = Bs + (wv * 32) * 64;

  const int lr = lane & 15;
  const int lq = lane >> 4;
  const int waveM = wv & 1;
  const int waveN = wv >> 1;
  const int lrm = lr & 7;  // row&7 for swizzle

  f32x4 acc[4][4] = {};

  for (int kk = 0; kk < KTOT; kk += 64) {
#pragma unroll
    for (int i = 0; i < 4; ++i) {
      gload16(gA + kk + (size_t)(i * 8) * KTOT, lA + i * 8 * 64);
      gload16(gB + kk + (size_t)(i * 8) * KTOT, lB + i * 8 * 64);
    }
    __syncthreads();  // drains vmcnt (global_load_lds) for all waves

#pragma unroll
    for (int kh = 0; kh < 2; ++kh) {
      bf16x8 af[4], bfr[4];
#pragma unroll
      for (int mi = 0; mi < 4; ++mi)
        af[mi] = *(const bf16x8*)(&As[(waveM * 64 + mi * 16 + lr) * 64 +
                                      ((kh * 4 + lq) ^ lrm) * 8]);
#pragma unroll
      for (int ni = 0; ni < 4; ++ni)
        bfr[ni] = *(const bf16x8*)(&Bs[(waveN * 64 + ni * 16 + lr) * 64 +
                                       ((kh * 4 + lq) ^ lrm) * 8]);
#pragma unroll
      for (int mi = 0; mi < 4; ++mi)
#pragma unroll
        for (int ni = 0; ni < 4; ++ni)
          acc[mi][ni] = __builtin_amdgcn_mfma_f32_16x16x32_bf16(
              af[mi], bfr[ni], acc[mi][ni], 0, 0, 0);
    }
    __syncthreads();
  }

  // Epilogue: C layout col=lane&15, row=(lane>>4)*4+reg. Physical col n:
  // even=re, odd=im of h=n>>1; col parity == lane parity -> shfl_xor(1).
  const int col = lane & 15;
  const int row0 = (lane >> 4) * 4;
  const int parity = lane & 1;
#pragma unroll
  for (int ni = 0; ni < 4; ++ni) {
    const int n = nBase + waveN * 64 + ni * 16 + col;
    const float bet = beta[n >> 1];
#pragma unroll
    for (int mi = 0; mi < 4; ++mi) {
      const int mrow = mBase + waveM * 64 + mi * 16 + row0;
#pragma unroll
      for (int r = 0; r < 4; ++r) {
        float a = acc[mi][ni][r];
        float o = __shfl_xor(a, 1);
        float re = parity ? o : a;
        float im = parity ? a : o;
        float mag = sqrtf(re * re + im * im);
        float s = mag + bet;
        float val;
        if (s <= 0.f)
          val = 0.f;
        else if (mag > 0.f)
          val = (parity ? im : re) * (s / mag);
        else
          val = parity ? 0.f : s;  // angle(0)==0 -> exp(i0)==1
        out[(size_t)(mrow + r) * 1024 + n] = val;
      }
    }
  }
}

// ---------------------------------------------------------------------------
extern "C" void kernel_launch(void* const* d_in, const int* in_sizes, int n_in,
                              void* d_out, int out_size, void* d_ws,
                              size_t ws_size, hipStream_t stream) {
  const float* x = (const float*)d_in[0];
  const float* hxre = (const float*)d_in[1];
  const float* hxim = (const float*)d_in[2];
  const float* ang = (const float*)d_in[3];
  const float* rre = (const float*)d_in[4];
  const float* rim = (const float*)d_in[5];
  const float* wre = (const float*)d_in[6];
  const float* wim = (const float*)d_in[7];
  const float* beta = (const float*)d_in[8];
  const int* perm = (const int*)d_in[9];

  char* ws = (char*)d_ws;
  bf16* Bm = (bf16*)ws;                               // 1024x1280 bf16, 2.5 MiB
  bf16* Apack = (bf16*)(ws + (size_t)1024 * KTOT * 2);  // 16384x1280 bf16, 40 MiB

  build_U<<<512, 256, 0, stream>>>(ang, rre, rim, wre, wim, perm, Bm);
  pack_A<<<(NB * 160) / 256, 256, 0, stream>>>(hxre, hxim, x, Apack);
  gemm_fused<<<1024, 256, 0, stream>>>(Apack, Bm, beta, (float*)d_out);
}

// Round 5
// 200.403 us; speedup vs baseline: 1.4886x; 1.1132x over previous
//
#include <hip/hip_runtime.h>
#include <hip/hip_bf16.h>
#include <stdint.h>
#include <stddef.h>

typedef __bf16 bf16;
typedef bf16 bf16x8 __attribute__((ext_vector_type(8)));
typedef float f32x4 __attribute__((ext_vector_type(4)));

#define EPSN 1e-8f
#define TWO_PI 6.283185307179586f

#define NB 16384   // batch
#define NH 512     // hidden
#define NI 256     // input
#define KTOT 1280  // 512 + 512 + 256

__device__ __forceinline__ float2 cmul(float2 a, float2 b) {
  return make_float2(a.x * b.x - a.y * b.y, a.x * b.y + a.y * b.x);
}
// a * conj(b)
__device__ __forceinline__ float2 cmulconj(float2 a, float2 b) {
  return make_float2(a.x * b.x + a.y * b.y, a.y * b.x - a.x * b.y);
}
__device__ __forceinline__ float2 cadd(float2 a, float2 b) {
  return make_float2(a.x + b.x, a.y + b.y);
}
__device__ __forceinline__ int brev9(int i) {
  return (int)(__brev((unsigned)i) >> 23);
}

// async global->LDS, 16B per lane; lds dest = wave-uniform base + lane*16
__device__ __forceinline__ void gload16(const bf16* g, bf16* l) {
  __builtin_amdgcn_global_load_lds(
      (const __attribute__((address_space(1))) void*)g,
      (__attribute__((address_space(3))) void*)l, 16, 0, 0);
}

// ---------------------------------------------------------------------------
// prep: blocks [0,512) = build_U column j (fused setup + pack_W, as round 4);
//       blocks [512, 10752) = pack_A octets. Fusing overlaps build_U's
//       latency-bound 512 blocks with pack_A's bandwidth stream.
//
// Bm[2h  ][k] = [ U_re[h,:] | -U_im[h,:] | W_re[h,:] ]
// Bm[2h+1][k] = [ U_im[h,:] |  U_re[h,:] | W_im[h,:] ]
// Apack[b][0:512|512:1024|1024:1280] = bf16([hxre|hxim|x][b])
// ---------------------------------------------------------------------------
__global__ __launch_bounds__(256) void prep(
    const float* __restrict__ ang, const float* __restrict__ rre,
    const float* __restrict__ rim, const float* __restrict__ wre,
    const float* __restrict__ wim, const int* __restrict__ perm,
    const float* __restrict__ hxre, const float* __restrict__ hxim,
    const float* __restrict__ x, bf16* __restrict__ Bm,
    bf16* __restrict__ Apack) {
  __shared__ float2 bufA[512];
  __shared__ float2 bufB[512];
  __shared__ float2 redw[4];
  __shared__ float2 bc;
  __shared__ float2 red2[256];

  const int bid = blockIdx.x;
  const int t = threadIdx.x;

  if (bid >= 512) {
    // ---------------- pack_A ----------------
    const int tid = (bid - 512) * 256 + t;  // 0 .. 16384*160-1
    const int b = tid / 160;
    const int o = tid - b * 160;
    const float* src;
    if (o < 64)
      src = hxre + (size_t)b * 512 + o * 8;
    else if (o < 128)
      src = hxim + (size_t)b * 512 + (o - 64) * 8;
    else
      src = x + (size_t)b * 256 + (o - 128) * 8;
    float4 f0 = ((const float4*)src)[0];
    float4 f1 = ((const float4*)src)[1];
    bf16x8 v;
    v[0] = (bf16)f0.x; v[1] = (bf16)f0.y; v[2] = (bf16)f0.z; v[3] = (bf16)f0.w;
    v[4] = (bf16)f1.x; v[5] = (bf16)f1.y; v[6] = (bf16)f1.z; v[7] = (bf16)f1.w;
    *(bf16x8*)(Apack + (size_t)b * KTOT + o * 8) = v;
    return;
  }

  // ---------------- build_U for column j = bid ----------------
  const int j = bid;
  const int j0 = t, j1 = t + 256;

  // norms of r1, r2 (per-block redundant, trivial)
  const float r1x0 = rre[j0], r1y0 = rim[j0];
  const float r1x1 = rre[j1], r1y1 = rim[j1];
  const float r2x0 = rre[512 + j0], r2y0 = rim[512 + j0];
  const float r2x1 = rre[512 + j1], r2y1 = rim[512 + j1];
  red2[t] = make_float2(r1x0 * r1x0 + r1y0 * r1y0 + r1x1 * r1x1 + r1y1 * r1y1,
                        r2x0 * r2x0 + r2y0 * r2y0 + r2x1 * r2x1 + r2y1 * r2y1);
  __syncthreads();
  for (int off = 128; off > 0; off >>= 1) {
    if (t < off) {
      red2[t].x += red2[t + off].x;
      red2[t].y += red2[t + off].y;
    }
    __syncthreads();
  }
  const float inv1 = 1.0f / (sqrtf(red2[0].x) + EPSN);
  const float inv2 = 1.0f / (sqrtf(red2[0].y) + EPSN);
  const float2 v1a = make_float2(r1x0 * inv1, r1y0 * inv1);
  const float2 v1b = make_float2(r1x1 * inv1, r1y1 * inv1);
  const float2 v2a = make_float2(r2x0 * inv2, r2y0 * inv2);
  const float2 v2b = make_float2(r2x1 * inv2, r2y1 * inv2);

  // init: after D1, spike d1[j] at position j; bit-rev scatter
  {
    float sj, cj;
    __sincosf(ang[j], &sj, &cj);
    const float2 dj = make_float2(cj, sj);
    float2 z = make_float2(0.f, 0.f);
    bufA[brev9(j0)] = (j0 == j) ? dj : z;
    bufA[brev9(j1)] = (j1 == j) ? dj : z;
  }
  __syncthreads();

  // forward FFT
#pragma unroll
  for (int st = 0; st < 9; ++st) {
    const int half = 1 << st;
    const int pos = t & (half - 1);
    const int i0 = ((t >> st) << (st + 1)) + pos;
    const int i1 = i0 + half;
    const float angv = -TWO_PI * (float)pos / (float)(2 << st);
    float sn, cs;
    __sincosf(angv, &sn, &cs);
    float2 u = bufA[i0];
    float2 w = bufA[i1];
    float2 tw = make_float2(cs * w.x - sn * w.y, cs * w.y + sn * w.x);
    bufA[i0] = make_float2(u.x + tw.x, u.y + tw.y);
    bufA[i1] = make_float2(u.x - tw.x, u.y - tw.y);
    __syncthreads();
  }

  // dot1 = sum_i h_i * v1_i
  {
    float2 p = cadd(cmul(bufA[j0], v1a), cmul(bufA[j1], v1b));
    for (int off = 32; off > 0; off >>= 1) {
      p.x += __shfl_down(p.x, off);
      p.y += __shfl_down(p.y, off);
    }
    if ((t & 63) == 0) redw[t >> 6] = p;
    __syncthreads();
    if (t == 0) bc = cadd(cadd(redw[0], redw[1]), cadd(redw[2], redw[3]));
    __syncthreads();
  }
  const float2 dot1 = bc;

  // Householder 1
  {
    float2 c0 = cmulconj(dot1, v1a);
    float2 c1 = cmulconj(dot1, v1b);
    float2 a0 = bufA[j0], a1 = bufA[j1];
    bufA[j0] = make_float2(a0.x - 2.f * c0.x, a0.y - 2.f * c0.y);
    bufA[j1] = make_float2(a1.x - 2.f * c1.x, a1.y - 2.f * c1.y);
  }
  __syncthreads();

  // permute + x d2 + bit-rev scatter
  {
    int p0 = perm[j0], p1 = perm[j1];
    float s0, c0, s1, c1;
    __sincosf(ang[512 + j0], &s0, &c0);
    __sincosf(ang[512 + j1], &s1, &c1);
    float2 g0 = cmul(make_float2(c0, s0), bufA[p0]);
    float2 g1 = cmul(make_float2(c1, s1), bufA[p1]);
    bufB[brev9(j0)] = g0;
    bufB[brev9(j1)] = g1;
  }
  __syncthreads();

  // inverse FFT (unscaled)
#pragma unroll
  for (int st = 0; st < 9; ++st) {
    const int half = 1 << st;
    const int pos = t & (half - 1);
    const int i0 = ((t >> st) << (st + 1)) + pos;
    const int i1 = i0 + half;
    const float angv = TWO_PI * (float)pos / (float)(2 << st);
    float sn, cs;
    __sincosf(angv, &sn, &cs);
    float2 u = bufB[i0];
    float2 w = bufB[i1];
    float2 tw = make_float2(cs * w.x - sn * w.y, cs * w.y + sn * w.x);
    bufB[i0] = make_float2(u.x + tw.x, u.y + tw.y);
    bufB[i1] = make_float2(u.x - tw.x, u.y - tw.y);
    __syncthreads();
  }

  // dot2 on unscaled ifft output
  {
    float2 q = cadd(cmul(bufB[j0], v2a), cmul(bufB[j1], v2b));
    for (int off = 32; off > 0; off >>= 1) {
      q.x += __shfl_down(q.x, off);
      q.y += __shfl_down(q.y, off);
    }
    if ((t & 63) == 0) redw[t >> 6] = q;
    __syncthreads();
    if (t == 0) bc = cadd(cadd(redw[0], redw[1]), cadd(redw[2], redw[3]));
    __syncthreads();
  }
  const float invN = 1.0f / 512.0f;
  const float2 dot2 = make_float2(bc.x * invN, bc.y * invN);

  // Householder2 + d3, scatter U[:,j] into Bm
#pragma unroll
  for (int e = 0; e < 2; ++e) {
    const int i = (e == 0) ? j0 : j1;
    const float2 vj = (e == 0) ? v2a : v2b;
    float2 h2 = make_float2(bufB[i].x * invN, bufB[i].y * invN);
    float2 c2 = cmulconj(dot2, vj);
    float2 hh = make_float2(h2.x - 2.f * c2.x, h2.y - 2.f * c2.y);
    float s3, c3;
    __sincosf(ang[1024 + i], &s3, &c3);
    float2 u = cmul(make_float2(c3, s3), hh);  // U[i][j]
    bf16* r0 = Bm + (size_t)(2 * i) * KTOT;
    bf16* r1 = Bm + (size_t)(2 * i + 1) * KTOT;
    r0[j] = (bf16)u.x;
    r0[512 + j] = (bf16)(-u.y);
    r1[j] = (bf16)u.y;
    r1[512 + j] = (bf16)u.x;
  }

  // pack_W for h = j
  Bm[(size_t)(2 * j) * KTOT + 1024 + t] = (bf16)wre[j * NI + t];
  Bm[(size_t)(2 * j + 1) * KTOT + 1024 + t] = (bf16)wim[j * NI + t];
}

// ---------------------------------------------------------------------------
// Fused GEMM + ModReLU: out[b,n] = ModReLU-comp( Apack[b,:] . Bm[n,:] ).
// M=16384, N=1024, K=1280. 128x128 tile, BK=64, **512 threads = 8 waves**
// (2M x 4N, each wave 64x32 = 4x2 frags of 16x16x32) -> acc = 32 AGPR,
// total regs/wave <= 128 -> 4 waves/SIMD -> 2 blocks/CU -> grid 1024 runs
// as exactly 2 full-capacity rounds (round-4's 96+64=160 regs gave 3
// blocks/CU and a ragged 1.33-round schedule = the 22% MfmaUtil ceiling).
//
// XOR chunk swizzle (round 4, conflict-free): LDS physical chunk p of row r
// holds logical chunk p^(r&7); staging permutes the GLOBAL source chunk
// ((lane&7)^(lane>>3)) since global_load_lds's LDS dest is fixed at
// base+lane*16B. Fragment reads use chunk (kh*4+lq)^(lr&7).
//
// XCD swizzle: id&7 -> XCD; each XCD owns 16 M-panels (A single-L2-resident).
// ---------------------------------------------------------------------------
__global__ __launch_bounds__(512, 4) void gemm_fused(
    const bf16* __restrict__ Apack, const bf16* __restrict__ Bm,
    const float* __restrict__ beta, float* __restrict__ out) {
  __shared__ bf16 As[128 * 64];
  __shared__ bf16 Bs[128 * 64];

  const int t = threadIdx.x;
  const int lane = t & 63;
  const int wv = t >> 6;  // 0..7

  const int id = blockIdx.x;  // 0..1023
  const int xcd = id & 7;
  const int lix = id >> 3;    // 0..127
  const int mBase = (xcd * 16 + (lix >> 3)) * 128;
  const int nBase = (lix & 7) * 128;

  // staging: wave wv stages A rows [wv*16, wv*16+16) and B rows same,
  // 2 gloads each (one gload = 8 rows: 64 lanes x 16B).
  const int subrow = lane >> 3;
  const int soct = (lane & 7) ^ subrow;  // XOR chunk swizzle
  const int srow = wv * 16 + subrow;
  const bf16* gA = Apack + (size_t)(mBase + srow) * KTOT + soct * 8;
  const bf16* gB = Bm + (size_t)(nBase + srow) * KTOT + soct * 8;
  bf16* lA = As + (wv * 16) * 64;
  bf16* lB = Bs + (wv * 16) * 64;

  const int lr = lane & 15;
  const int lq = lane >> 4;
  const int lrm = lr & 7;
  const int waveM = wv & 1;   // 2 M positions x 64 rows
  const int waveN = wv >> 1;  // 4 N positions x 32 cols

  f32x4 acc[4][2] = {};

  for (int kk = 0; kk < KTOT; kk += 64) {
    gload16(gA + kk, lA);
    gload16(gA + kk + (size_t)8 * KTOT, lA + 8 * 64);
    gload16(gB + kk, lB);
    gload16(gB + kk + (size_t)8 * KTOT, lB + 8 * 64);
    __syncthreads();  // drains vmcnt for all waves

#pragma unroll
    for (int kh = 0; kh < 2; ++kh) {
      const int co = ((kh * 4 + lq) ^ lrm) * 8;
      bf16x8 af[4], bfr[2];
#pragma unroll
      for (int mi = 0; mi < 4; ++mi)
        af[mi] = *(const bf16x8*)(&As[(waveM * 64 + mi * 16 + lr) * 64 + co]);
#pragma unroll
      for (int ni = 0; ni < 2; ++ni)
        bfr[ni] = *(const bf16x8*)(&Bs[(waveN * 32 + ni * 16 + lr) * 64 + co]);
#pragma unroll
      for (int mi = 0; mi < 4; ++mi)
#pragma unroll
        for (int ni = 0; ni < 2; ++ni)
          acc[mi][ni] = __builtin_amdgcn_mfma_f32_16x16x32_bf16(
              af[mi], bfr[ni], acc[mi][ni], 0, 0, 0);
    }
    __syncthreads();
  }

  // Epilogue: C layout col=lane&15, row=(lane>>4)*4+reg. Physical col n:
  // even=re, odd=im of h=n>>1; col parity == lane parity -> shfl_xor(1).
  const int col = lane & 15;
  const int row0 = lq * 4;
  const int parity = lane & 1;
#pragma unroll
  for (int ni = 0; ni < 2; ++ni) {
    const int n = nBase + waveN * 32 + ni * 16 + col;
    const float bet = beta[n >> 1];
#pragma unroll
    for (int mi = 0; mi < 4; ++mi) {
      const int mrow = mBase + waveM * 64 + mi * 16 + row0;
#pragma unroll
      for (int r = 0; r < 4; ++r) {
        float a = acc[mi][ni][r];
        float o = __shfl_xor(a, 1);
        float re = parity ? o : a;
        float im = parity ? a : o;
        float mag2 = re * re + im * im;
        float val;
        if (mag2 > 0.f) {
          float rs = __frsqrt_rn(mag2);      // 1/mag
          float s = mag2 * rs + bet;         // mag + beta
          val = (s > 0.f) ? (parity ? im : re) * (s * rs) : 0.f;
        } else {
          val = (bet > 0.f && parity == 0) ? bet : 0.f;  // angle(0)==0
        }
        out[(size_t)(mrow + r) * 1024 + n] = val;
      }
    }
  }
}

// ---------------------------------------------------------------------------
extern "C" void kernel_launch(void* const* d_in, const int* in_sizes, int n_in,
                              void* d_out, int out_size, void* d_ws,
                              size_t ws_size, hipStream_t stream) {
  const float* x = (const float*)d_in[0];
  const float* hxre = (const float*)d_in[1];
  const float* hxim = (const float*)d_in[2];
  const float* ang = (const float*)d_in[3];
  const float* rre = (const float*)d_in[4];
  const float* rim = (const float*)d_in[5];
  const float* wre = (const float*)d_in[6];
  const float* wim = (const float*)d_in[7];
  const float* beta = (const float*)d_in[8];
  const int* perm = (const int*)d_in[9];

  char* ws = (char*)d_ws;
  bf16* Bm = (bf16*)ws;                                 // 1024x1280 bf16, 2.5 MiB
  bf16* Apack = (bf16*)(ws + (size_t)1024 * KTOT * 2);  // 16384x1280 bf16, 40 MiB

  prep<<<512 + (NB * 160) / 256, 256, 0, stream>>>(ang, rre, rim, wre, wim,
                                                   perm, hxre, hxim, x, Bm,
                                                   Apack);
  gemm_fused<<<1024, 512, 0, stream>>>(Apack, Bm, beta, (float*)d_out);
}